// Round 12
// baseline (710.238 us; speedup 1.0000x reference)
//
#include <hip/hip_runtime.h>

#define EN 200000
#define TN 1500000
#define NCHUNK ((TN + 63) >> 6)
#define SCAN_BLK 512
#define NB ((EN + SCAN_BLK - 1) / SCAN_BLK)

typedef short s16x8 __attribute__((ext_vector_type(8)));
typedef float f32x4 __attribute__((ext_vector_type(4)));

// ---- packed weight offsets (ushort units) ----
#define WJI   0
#define WKJ   16384
#define WDOWN 32768
#define WUP   40960
#define WB0   49152
#define WB1   65536
#define WLIN  81920
#define WA00  98304
#define WA01  114688
#define WA10  131072
#define WA11  147456
#define WSBFP 163840
#define WP_COUNT 167936

// hardware bf16 convert (RNE) — fast path for VALU-bound edge kernels
__device__ __forceinline__ unsigned short f2bf(float f) {
    unsigned int r;
    asm("v_cvt_pk_bf16_f32 %0, %1, %1" : "=v"(r) : "v"(f));
    return (unsigned short)r;
}
// bit-twiddle RNE convert — used in k_mscat (A/B: asm variant cost 25% there)
__device__ __forceinline__ unsigned short f2bf_o(float f) {
    unsigned int b = __float_as_uint(f);
    b += 0x7FFFu + ((b >> 16) & 1u);
    return (unsigned short)(b >> 16);
}
__device__ __forceinline__ float bf2f(unsigned short u) {
    return __uint_as_float(((unsigned int)u) << 16);
}
__device__ __forceinline__ float silu_f(float v) {
    return v * __builtin_amdgcn_rcpf(1.f + __expf(-v));
}

#define MFMA(a, b, c) __builtin_amdgcn_mfma_f32_16x16x32_bf16((a), (b), (c), 0, 0, 0)

// ============ prep1: combine tiny basis weight pairs ============
__global__ void k_prep1(const float* __restrict__ Wr1, const float* __restrict__ Wr2,
                        const float* __restrict__ Ws1, const float* __restrict__ Ws2,
                        float* __restrict__ wrbfc, float* __restrict__ wsbfc) {
    int idx = blockIdx.x * 256 + threadIdx.x;
    if (idx < 768) {  // [6][128]
        int r = idx >> 7, c = idx & 127;
        float s = 0.f;
        #pragma unroll
        for (int m = 0; m < 8; m++) s += Wr1[r * 8 + m] * Wr2[m * 128 + c];
        wrbfc[idx] = s;
    }
    int i2 = idx - 768;
    if (i2 >= 0 && i2 < 2688) {  // [42][64]
        int r = i2 >> 6, c = i2 & 63;
        float s = 0.f;
        #pragma unroll
        for (int m = 0; m < 8; m++) s += Ws1[r * 8 + m] * Ws2[m * 64 + c];
        wsbfc[i2] = s;
    }
}

// ============ prep2: pack weights into MFMA B-fragment layout ============
__global__ void k_prep2(const float* __restrict__ Wji, const float* __restrict__ Wkj,
                        const float* __restrict__ Wdown, const float* __restrict__ Wup,
                        const float* __restrict__ Wbef, const float* __restrict__ Wlin,
                        const float* __restrict__ Waft, const float* __restrict__ wsbfc,
                        unsigned short* __restrict__ wp) {
    for (int idx = blockIdx.x * 256 + threadIdx.x; idx < WP_COUNT; idx += gridDim.x * 256) {
        const float* src;
        int off, N;
        bool pad42 = false;
        if (idx < WKJ)        { src = Wji;           off = WJI;   N = 128; }
        else if (idx < WDOWN) { src = Wkj;           off = WKJ;   N = 128; }
        else if (idx < WUP)   { src = Wdown;         off = WDOWN; N = 64;  }
        else if (idx < WB0)   { src = Wup;           off = WUP;   N = 128; }
        else if (idx < WB1)   { src = Wbef;          off = WB0;   N = 128; }
        else if (idx < WLIN)  { src = Wbef + 16384;  off = WB1;   N = 128; }
        else if (idx < WA00)  { src = Wlin;          off = WLIN;  N = 128; }
        else if (idx < WA01)  { src = Waft;          off = WA00;  N = 128; }
        else if (idx < WA10)  { src = Waft + 16384;  off = WA01;  N = 128; }
        else if (idx < WA11)  { src = Waft + 32768;  off = WA10;  N = 128; }
        else if (idx < WSBFP) { src = Waft + 49152;  off = WA11;  N = 128; }
        else                  { src = wsbfc;         off = WSBFP; N = 64; pad42 = true; }
        int li = idx - off;
        int j = li & 7, lane = (li >> 3) & 63, rest = li >> 9;
        int ncb = N >> 4;
        int cb = rest % ncb, ks = rest / ncb;
        int k = ks * 32 + ((lane >> 4) << 3) + j;
        int n = cb * 16 + (lane & 15);
        float v = 0.f;
        if (!pad42 || k < 42) v = src[k * N + n];
        wp[idx] = f2bf(v);
    }
}

// ============ K1: edge stage 1 ============
__global__ __launch_bounds__(256, 4) void k_edge1(
        const float* __restrict__ x, const float* __restrict__ rbf,
        const float* __restrict__ bkj, const float* __restrict__ bji,
        const unsigned short* __restrict__ wp, const float* __restrict__ wrbfc,
        float* __restrict__ xji, unsigned short* __restrict__ xd) {
    __shared__ unsigned short xa[64 * 136];
    __shared__ unsigned short kjt[64 * 136];   // holds rp first, then kj tile
    const int tid = threadIdx.x;
    const int row0 = blockIdx.x * 64;
    {
        const float4* src = (const float4*)(x + (size_t)row0 * 128);
        #pragma unroll
        for (int k = 0; k < 8; k++) {
            int idx = tid + k * 256;
            float4 v = src[idx];
            int flat = idx << 2, r = flat >> 7, c = flat & 127;
            ushort4 u; u.x = f2bf(v.x); u.y = f2bf(v.y); u.z = f2bf(v.z); u.w = f2bf(v.w);
            *(ushort4*)&xa[r * 136 + c] = u;
        }
    }
    #pragma unroll
    for (int k = 0; k < 32; k++) {
        int idx = tid + k * 256;
        int r = idx >> 7, c = idx & 127;
        const float* rb = rbf + (size_t)(row0 + r) * 6;
        float s = rb[0] * wrbfc[c] + rb[1] * wrbfc[128 + c] + rb[2] * wrbfc[256 + c]
                + rb[3] * wrbfc[384 + c] + rb[4] * wrbfc[512 + c] + rb[5] * wrbfc[640 + c];
        kjt[r * 136 + c] = f2bf(s);
    }
    __syncthreads();
    const int w = tid >> 6, l = tid & 63, l15 = l & 15, l4 = l >> 4;
    s16x8 af[4];
    {
        const unsigned short* ab = &xa[(w * 16 + l15) * 136 + l4 * 8];
        #pragma unroll
        for (int ks = 0; ks < 4; ks++) af[ks] = *(const s16x8*)(ab + ks * 32);
    }
    #pragma unroll
    for (int cb = 0; cb < 8; cb++) {
        f32x4 accj = {0.f, 0.f, 0.f, 0.f};
        f32x4 acck = {0.f, 0.f, 0.f, 0.f};
        #pragma unroll
        for (int ks = 0; ks < 4; ks++) {
            s16x8 bfj = *(const s16x8*)(wp + WJI + (((ks << 3) + cb) * 64 + l) * 8);
            s16x8 bfk = *(const s16x8*)(wp + WKJ + (((ks << 3) + cb) * 64 + l) * 8);
            accj = MFMA(af[ks], bfj, accj);
            acck = MFMA(af[ks], bfk, acck);
        }
        int col = (cb << 4) + l15;
        float bvj = bji[col];
        float bvk = bkj[col];
        #pragma unroll
        for (int i = 0; i < 4; i++) {
            int r = w * 16 + l4 * 4 + i;
            xji[(size_t)(row0 + r) * 128 + col] = silu_f(accj[i] + bvj);
            float rp = bf2f(kjt[r * 136 + col]);
            kjt[r * 136 + col] = f2bf(silu_f(acck[i] + bvk) * rp);
        }
    }
    __syncthreads();
    s16x8 ag[4];
    {
        const unsigned short* ab = &kjt[(w * 16 + l15) * 136 + l4 * 8];
        #pragma unroll
        for (int ks = 0; ks < 4; ks++) ag[ks] = *(const s16x8*)(ab + ks * 32);
    }
    #pragma unroll
    for (int cb = 0; cb < 4; cb++) {
        f32x4 acc = {0.f, 0.f, 0.f, 0.f};
        #pragma unroll
        for (int ks = 0; ks < 4; ks++) {
            s16x8 bf = *(const s16x8*)(wp + WDOWN + (((ks << 2) + cb) * 64 + l) * 8);
            acc = MFMA(ag[ks], bf, acc);
        }
        int col = (cb << 4) + l15;
        #pragma unroll
        for (int i = 0; i < 4; i++) {
            int r = w * 16 + l4 * 4 + i;
            xd[(size_t)(row0 + r) * 64 + col] = f2bf(silu_f(acc[i]));
        }
    }
}

// ============ sort phase ============
__global__ void k_hist(const int* __restrict__ iji, int* __restrict__ cnt) {
    for (int t = blockIdx.x * 256 + threadIdx.x; t < TN; t += gridDim.x * 256)
        atomicAdd(&cnt[iji[t]], 1);
}

__global__ __launch_bounds__(SCAN_BLK) void k_scan1(const int* __restrict__ cnt, int* __restrict__ bsum) {
    __shared__ int s[SCAN_BLK];
    int i = threadIdx.x, gi = blockIdx.x * SCAN_BLK + i;
    s[i] = (gi < EN) ? cnt[gi] : 0;
    __syncthreads();
    for (int d = SCAN_BLK >> 1; d > 0; d >>= 1) {
        if (i < d) s[i] += s[i + d];
        __syncthreads();
    }
    if (i == 0) bsum[blockIdx.x] = s[0];
}

__global__ __launch_bounds__(SCAN_BLK) void k_scan2(const int* __restrict__ bsum, int* __restrict__ bscan) {
    __shared__ int s[SCAN_BLK];
    int i = threadIdx.x;
    int v = (i < NB) ? bsum[i] : 0;
    s[i] = v;
    __syncthreads();
    for (int d = 1; d < SCAN_BLK; d <<= 1) {
        int t = (i >= d) ? s[i - d] : 0;
        __syncthreads();
        s[i] += t;
        __syncthreads();
    }
    if (i < NB) bscan[i] = s[i] - v;
}

__global__ __launch_bounds__(SCAN_BLK) void k_scan3(const int* __restrict__ cnt, const int* __restrict__ bscan,
                                                    int* __restrict__ segoff, int* __restrict__ cursor) {
    __shared__ int s[SCAN_BLK];
    int i = threadIdx.x, gi = blockIdx.x * SCAN_BLK + i;
    int c = (gi < EN) ? cnt[gi] : 0;
    s[i] = c;
    __syncthreads();
    for (int d = 1; d < SCAN_BLK; d <<= 1) {
        int t = (i >= d) ? s[i - d] : 0;
        __syncthreads();
        s[i] += t;
        __syncthreads();
    }
    int off = bscan[blockIdx.x] + s[i] - c;
    if (gi < EN) { segoff[gi] = off; cursor[gi] = off; }
    if (blockIdx.x == 0 && i == 0) segoff[EN] = TN;
}

__global__ void k_rank(const int* __restrict__ iji, int* __restrict__ cursor, int* __restrict__ pos) {
    for (int t = blockIdx.x * 256 + threadIdx.x; t < TN; t += gridDim.x * 256)
        pos[t] = atomicAdd(&cursor[iji[t]], 1);
}

// ============ K2a: sbf_p GEMM + xd gather + scattered m store ============
// R8-exact memory pattern + register double-buffered sbf prefetch (hides
// staging latency under gather/scatter of the previous chunk).
__global__ __launch_bounds__(256) void k_mscat(
        const float* __restrict__ sbf, const int* __restrict__ ikj, const int* __restrict__ pos,
        const unsigned short* __restrict__ wp, const unsigned short* __restrict__ xd,
        unsigned short* __restrict__ msort) {
    __shared__ unsigned short sb[64 * 72];
    const int tid = threadIdx.x;
    const int w = tid >> 6, l = tid & 63, l15 = l & 15, l4 = l >> 4;
    for (int idx = tid; idx < 64 * 72; idx += 256) sb[idx] = 0;
    __syncthreads();
    int ch = blockIdx.x;
    float pf[11];
    if (ch < NCHUNK) {
        const float* src = sbf + (size_t)(ch << 6) * 42;
        int lim = min(2688, (TN - (ch << 6)) * 42);
        #pragma unroll
        for (int k = 0; k < 11; k++) {
            int idx = tid + (k << 8);
            pf[k] = (idx < lim) ? src[idx] : 0.f;
        }
    }
    for (; ch < NCHUNK; ch += gridDim.x) {
        const int t0 = ch << 6;
        const int nt = min(64, TN - t0);
        const int tot = nt * 42;
        #pragma unroll
        for (int k = 0; k < 11; k++) {
            int idx = tid + (k << 8);
            if (idx < tot) {
                int r = idx / 42, c = idx - r * 42;
                sb[r * 72 + c] = f2bf_o(pf[k]);
            }
        }
        __syncthreads();
        s16x8 afr[2];
        {
            const unsigned short* ab = &sb[(w * 16 + l15) * 72 + l4 * 8];
            afr[0] = *(const s16x8*)ab;
            afr[1] = *(const s16x8*)(ab + 32);
        }
        f32x4 accs[4];
        #pragma unroll
        for (int cb = 0; cb < 4; cb++) {
            f32x4 acc = {0.f, 0.f, 0.f, 0.f};
            acc = MFMA(afr[0], *(const s16x8*)(wp + WSBFP + ((cb) * 64 + l) * 8), acc);
            acc = MFMA(afr[1], *(const s16x8*)(wp + WSBFP + ((4 + cb) * 64 + l) * 8), acc);
            accs[cb] = acc;
        }
        // prefetch next chunk (overlaps the gather/scatter below)
        int nch = ch + gridDim.x;
        if (nch < NCHUNK) {
            const float* nsrc = sbf + (size_t)(nch << 6) * 42;
            int nlim = min(2688, (TN - (nch << 6)) * 42);
            #pragma unroll
            for (int k = 0; k < 11; k++) {
                int idx = tid + (k << 8);
                pf[k] = (idx < nlim) ? nsrc[idx] : 0.f;
            }
        }
        #pragma unroll
        for (int i = 0; i < 4; i++) {
            int r = w * 16 + l4 * 4 + i;
            if (r < nt) {
                int t = t0 + r;
                int a = ikj[t];
                size_t mb = (size_t)pos[t] * 64;
                const unsigned short* xr = xd + (size_t)a * 64;
                #pragma unroll
                for (int cb = 0; cb < 4; cb++) {
                    int col = (cb << 4) + l15;
                    msort[mb + col] = f2bf_o(accs[cb][i] * bf2f(xr[col]));
                }
            }
        }
        __syncthreads();
    }
}

// ============ fallback: atomic scatter ============
__global__ __launch_bounds__(256) void k_trip(
        const float* __restrict__ sbf, const int* __restrict__ ikj, const int* __restrict__ iji,
        const unsigned short* __restrict__ wp, const unsigned short* __restrict__ xd,
        float* __restrict__ agg) {
    __shared__ unsigned short sb[64 * 72];
    const int tid = threadIdx.x;
    const int w = tid >> 6, l = tid & 63, l15 = l & 15, l4 = l >> 4;
    for (int idx = tid; idx < 64 * 72; idx += 256) sb[idx] = 0;
    __syncthreads();
    for (int ch = blockIdx.x; ch < NCHUNK; ch += gridDim.x) {
        const int t0 = ch << 6;
        const int nt = min(64, TN - t0);
        const int tot = nt * 42;
        const float* src = sbf + (size_t)t0 * 42;
        for (int idx = tid; idx < tot; idx += 256) {
            int r = idx / 42, c = idx - r * 42;
            sb[r * 72 + c] = f2bf_o(src[idx]);
        }
        __syncthreads();
        s16x8 afr[2];
        {
            const unsigned short* ab = &sb[(w * 16 + l15) * 72 + l4 * 8];
            afr[0] = *(const s16x8*)ab;
            afr[1] = *(const s16x8*)(ab + 32);
        }
        #pragma unroll
        for (int cb = 0; cb < 4; cb++) {
            f32x4 acc = {0.f, 0.f, 0.f, 0.f};
            acc = MFMA(afr[0], *(const s16x8*)(wp + WSBFP + ((cb) * 64 + l) * 8), acc);
            acc = MFMA(afr[1], *(const s16x8*)(wp + WSBFP + ((4 + cb) * 64 + l) * 8), acc);
            int col = (cb << 4) + l15;
            #pragma unroll
            for (int i = 0; i < 4; i++) {
                int r = w * 16 + l4 * 4 + i;
                if (r < nt) {
                    int t = t0 + r;
                    int a = ikj[t], g = iji[t];
                    float m = acc[i] * bf2f(xd[(size_t)a * 64 + col]);
                    atomicAdd(&agg[(size_t)g * 64 + col], m);
                }
            }
        }
        __syncthreads();
    }
}

// residual MLP layer, h in registers; phases barrier-separated.
__device__ __forceinline__ void layer_reg(float (*h)[4], unsigned short* s0, unsigned short* s1,
                                          const unsigned short* wp0, const float* b0,
                                          const unsigned short* wp1, const float* b1,
                                          int w, int l, int l15, int l4) {
    #pragma unroll
    for (int cb = 0; cb < 8; cb++) {
        int col = (cb << 4) + l15;
        #pragma unroll
        for (int i = 0; i < 4; i++)
            s0[((w << 4) + (l4 << 2) + i) * 136 + col] = f2bf(h[cb][i]);
    }
    __syncthreads();
    {
        const unsigned short* ab = &s0[((w << 4) + l15) * 136 + (l4 << 3)];
        s16x8 a0 = *(const s16x8*)ab, a1 = *(const s16x8*)(ab + 32);
        s16x8 a2 = *(const s16x8*)(ab + 64), a3 = *(const s16x8*)(ab + 96);
        #pragma unroll
        for (int cb = 0; cb < 8; cb++) {
            f32x4 acc = {0.f, 0.f, 0.f, 0.f};
            acc = MFMA(a0, *(const s16x8*)(wp0 + ((cb) * 64 + l) * 8), acc);
            acc = MFMA(a1, *(const s16x8*)(wp0 + ((8 + cb) * 64 + l) * 8), acc);
            acc = MFMA(a2, *(const s16x8*)(wp0 + ((16 + cb) * 64 + l) * 8), acc);
            acc = MFMA(a3, *(const s16x8*)(wp0 + ((24 + cb) * 64 + l) * 8), acc);
            int col = (cb << 4) + l15;
            float bv = b0[col];
            #pragma unroll
            for (int i = 0; i < 4; i++)
                s1[((w << 4) + (l4 << 2) + i) * 136 + col] = f2bf(silu_f(acc[i] + bv));
        }
    }
    __syncthreads();
    {
        const unsigned short* ab = &s1[((w << 4) + l15) * 136 + (l4 << 3)];
        s16x8 a0 = *(const s16x8*)ab, a1 = *(const s16x8*)(ab + 32);
        s16x8 a2 = *(const s16x8*)(ab + 64), a3 = *(const s16x8*)(ab + 96);
        #pragma unroll
        for (int cb = 0; cb < 8; cb++) {
            f32x4 acc = {0.f, 0.f, 0.f, 0.f};
            acc = MFMA(a0, *(const s16x8*)(wp1 + ((cb) * 64 + l) * 8), acc);
            acc = MFMA(a1, *(const s16x8*)(wp1 + ((8 + cb) * 64 + l) * 8), acc);
            acc = MFMA(a2, *(const s16x8*)(wp1 + ((16 + cb) * 64 + l) * 8), acc);
            acc = MFMA(a3, *(const s16x8*)(wp1 + ((24 + cb) * 64 + l) * 8), acc);
            int col = (cb << 4) + l15;
            float bv = b1[col];
            #pragma unroll
            for (int i = 0; i < 4; i++) h[cb][i] += silu_f(acc[i] + bv);
        }
    }
    __syncthreads();
}

// shared body for edge stage 2 after aa holds the bf16 agg tile (stride 72)
__device__ __forceinline__ void edge2_body(
        unsigned short* aa, unsigned short* bb, const float* x,
        const unsigned short* wp, const float* bbef, const float* blin,
        const float* baft, float* out, int row0, int tid) {
    const int w = tid >> 6, l = tid & 63, l15 = l & 15, l4 = l >> 4;
    float h[8][4];
    #pragma unroll
    for (int cb = 0; cb < 8; cb++) {
        int col = (cb << 4) + l15;
        #pragma unroll
        for (int i = 0; i < 4; i++) {
            int r = (w << 4) + (l4 << 2) + i;
            h[cb][i] = out[(size_t)(row0 + r) * 128 + col];
        }
    }
    __syncthreads();
    {
        const unsigned short* ab = &aa[((w << 4) + l15) * 72 + (l4 << 3)];
        s16x8 a0 = *(const s16x8*)ab, a1 = *(const s16x8*)(ab + 32);
        #pragma unroll
        for (int cb = 0; cb < 8; cb++) {
            f32x4 acc = {0.f, 0.f, 0.f, 0.f};
            acc = MFMA(a0, *(const s16x8*)(wp + WUP + ((cb) * 64 + l) * 8), acc);
            acc = MFMA(a1, *(const s16x8*)(wp + WUP + ((8 + cb) * 64 + l) * 8), acc);
            #pragma unroll
            for (int i = 0; i < 4; i++) h[cb][i] += silu_f(acc[i]);
        }
    }
    __syncthreads();
    layer_reg(h, bb, aa, wp + WB0, bbef, wp + WB1, bbef + 128, w, l, l15, l4);
    #pragma unroll
    for (int cb = 0; cb < 8; cb++) {
        int col = (cb << 4) + l15;
        #pragma unroll
        for (int i = 0; i < 4; i++)
            bb[((w << 4) + (l4 << 2) + i) * 136 + col] = f2bf(h[cb][i]);
    }
    __syncthreads();
    {
        const unsigned short* ab = &bb[((w << 4) + l15) * 136 + (l4 << 3)];
        s16x8 a0 = *(const s16x8*)ab, a1 = *(const s16x8*)(ab + 32);
        s16x8 a2 = *(const s16x8*)(ab + 64), a3 = *(const s16x8*)(ab + 96);
        #pragma unroll
        for (int cb = 0; cb < 8; cb++) {
            f32x4 acc = {0.f, 0.f, 0.f, 0.f};
            acc = MFMA(a0, *(const s16x8*)(wp + WLIN + ((cb) * 64 + l) * 8), acc);
            acc = MFMA(a1, *(const s16x8*)(wp + WLIN + ((8 + cb) * 64 + l) * 8), acc);
            acc = MFMA(a2, *(const s16x8*)(wp + WLIN + ((16 + cb) * 64 + l) * 8), acc);
            acc = MFMA(a3, *(const s16x8*)(wp + WLIN + ((24 + cb) * 64 + l) * 8), acc);
            int col = (cb << 4) + l15;
            float bv = blin[col];
            #pragma unroll
            for (int i = 0; i < 4; i++) {
                int r = (w << 4) + (l4 << 2) + i;
                h[cb][i] = silu_f(acc[i] + bv) + x[(size_t)(row0 + r) * 128 + col];
            }
        }
    }
    __syncthreads();
    layer_reg(h, aa, bb, wp + WA00, baft, wp + WA01, baft + 128, w, l, l15, l4);
    layer_reg(h, aa, bb, wp + WA10, baft + 256, wp + WA11, baft + 384, w, l, l15, l4);
    #pragma unroll
    for (int cb = 0; cb < 8; cb++) {
        int col = (cb << 4) + l15;
        #pragma unroll
        for (int i = 0; i < 4; i++) {
            int r = (w << 4) + (l4 << 2) + i;
            out[(size_t)(row0 + r) * 128 + col] = h[cb][i];
        }
    }
}

// ============ K3 (sorted path): fused segment-reduce + edge stage 2 ============
// This block's 64 e-rows own the contiguous msort range segoff[row0]..segoff[row0+64].
__global__ __launch_bounds__(256, 4) void k_edge2f(
        const unsigned short* __restrict__ msort, const int* __restrict__ segoff,
        const float* __restrict__ x, const unsigned short* __restrict__ wp,
        const float* __restrict__ bbef, const float* __restrict__ blin,
        const float* __restrict__ baft, float* __restrict__ out) {
    __shared__ unsigned short aa[64 * 136];
    __shared__ unsigned short bb[64 * 136];
    __shared__ int soff[65];
    const int tid = threadIdx.x;
    const int row0 = blockIdx.x * 64;
    const int w = tid >> 6, l = tid & 63;
    if (tid < 65) soff[tid] = segoff[row0 + tid];
    __syncthreads();
    // segment reduce -> aa (bf16, stride 72); lane l = col l, coalesced 128B rows
    for (int r = w; r < 64; r += 4) {
        int n0 = soff[r], n1 = soff[r + 1];
        float s = 0.f;
        for (int p = n0; p < n1; p++)
            s += bf2f(msort[(size_t)p * 64 + l]);
        aa[r * 72 + l] = f2bf(s);
    }
    edge2_body(aa, bb, x, wp, bbef, blin, baft, out, row0, tid);
}

// ============ K3 (fallback path): agg-reading edge stage 2 ============
__global__ __launch_bounds__(256, 4) void k_edge2(
        const float* __restrict__ agg, const float* __restrict__ x,
        const unsigned short* __restrict__ wp, const float* __restrict__ bbef,
        const float* __restrict__ blin, const float* __restrict__ baft,
        float* __restrict__ out) {
    __shared__ unsigned short aa[64 * 136];
    __shared__ unsigned short bb[64 * 136];
    const int tid = threadIdx.x;
    const int row0 = blockIdx.x * 64;
    {
        const float4* src = (const float4*)(agg + (size_t)row0 * 64);
        #pragma unroll
        for (int k = 0; k < 4; k++) {
            int idx = tid + k * 256;
            float4 v = src[idx];
            int flat = idx << 2, r = flat >> 6, c = flat & 63;
            ushort4 u; u.x = f2bf(v.x); u.y = f2bf(v.y); u.z = f2bf(v.z); u.w = f2bf(v.w);
            *(ushort4*)&aa[r * 72 + c] = u;
        }
    }
    edge2_body(aa, bb, x, wp, bbef, blin, baft, out, row0, tid);
}

extern "C" void kernel_launch(void* const* d_in, const int* in_sizes, int n_in,
                              void* d_out, int out_size, void* d_ws, size_t ws_size,
                              hipStream_t stream) {
    const float* x     = (const float*)d_in[0];
    const float* rbf   = (const float*)d_in[1];
    const float* sbf   = (const float*)d_in[2];
    const int*   ikj   = (const int*)d_in[3];
    const int*   iji   = (const int*)d_in[4];
    const float* Wr1   = (const float*)d_in[5];
    const float* Wr2   = (const float*)d_in[6];
    const float* Ws1   = (const float*)d_in[7];
    const float* Ws2   = (const float*)d_in[8];
    const float* Wkj   = (const float*)d_in[9];
    const float* bkj   = (const float*)d_in[10];
    const float* Wji   = (const float*)d_in[11];
    const float* bji   = (const float*)d_in[12];
    const float* Wdown = (const float*)d_in[13];
    const float* Wup   = (const float*)d_in[14];
    const float* Wbef  = (const float*)d_in[15];
    const float* bbef  = (const float*)d_in[16];
    const float* Wlin  = (const float*)d_in[17];
    const float* blin  = (const float*)d_in[18];
    const float* Waft  = (const float*)d_in[19];
    const float* baft  = (const float*)d_in[20];

    char* ws = (char*)d_ws;
    size_t o = 0;
    auto alloc = [&](size_t bytes) { size_t r = o; o = (o + bytes + 255) & ~(size_t)255; return r; };
    size_t o_agg   = alloc((size_t)EN * 64 * 4);
    size_t o_xd    = alloc((size_t)EN * 64 * 2);
    size_t o_wp    = alloc((size_t)WP_COUNT * 2);
    size_t o_wrbfc = alloc(768 * 4);
    size_t o_wsbfc = alloc(2688 * 4);
    size_t o_cnt   = alloc((size_t)EN * 4);
    size_t o_soff  = alloc((size_t)(EN + 1) * 4);
    size_t o_cur   = alloc((size_t)EN * 4);
    size_t o_bsum  = alloc(SCAN_BLK * 4);
    size_t o_bscan = alloc(SCAN_BLK * 4);
    size_t o_pos   = alloc((size_t)TN * 4);
    size_t o_msort = alloc((size_t)TN * 64 * 2);
    size_t need_sorted = o;

    float* agg          = (float*)(ws + o_agg);
    unsigned short* xd  = (unsigned short*)(ws + o_xd);
    unsigned short* wp  = (unsigned short*)(ws + o_wp);
    float* wrbfc        = (float*)(ws + o_wrbfc);
    float* wsbfc        = (float*)(ws + o_wsbfc);
    int* cnt            = (int*)(ws + o_cnt);
    int* segoff         = (int*)(ws + o_soff);
    int* cursor         = (int*)(ws + o_cur);
    int* bsum           = (int*)(ws + o_bsum);
    int* bscan          = (int*)(ws + o_bscan);
    int* pos            = (int*)(ws + o_pos);
    unsigned short* msort = (unsigned short*)(ws + o_msort);
    float* out          = (float*)d_out;

    k_prep1<<<14, 256, 0, stream>>>(Wr1, Wr2, Ws1, Ws2, wrbfc, wsbfc);
    k_prep2<<<656, 256, 0, stream>>>(Wji, Wkj, Wdown, Wup, Wbef, Wlin, Waft, wsbfc, wp);
    k_edge1<<<EN / 64, 256, 0, stream>>>(x, rbf, bkj, bji, wp, wrbfc, out, xd);

    if (ws_size >= need_sorted) {
        hipMemsetAsync(cnt, 0, (size_t)EN * 4, stream);
        k_hist<<<2048, 256, 0, stream>>>(iji, cnt);
        k_scan1<<<NB, SCAN_BLK, 0, stream>>>(cnt, bsum);
        k_scan2<<<1, SCAN_BLK, 0, stream>>>(bsum, bscan);
        k_scan3<<<NB, SCAN_BLK, 0, stream>>>(cnt, bscan, segoff, cursor);
        k_rank<<<2048, 256, 0, stream>>>(iji, cursor, pos);
        k_mscat<<<4096, 256, 0, stream>>>(sbf, ikj, pos, wp, xd, msort);
        k_edge2f<<<EN / 64, 256, 0, stream>>>(msort, segoff, x, wp, bbef, blin, baft, out);
    } else {
        hipMemsetAsync(agg, 0, (size_t)EN * 64 * 4, stream);
        k_trip<<<4096, 256, 0, stream>>>(sbf, ikj, iji, wp, xd, agg);
        k_edge2<<<EN / 64, 256, 0, stream>>>(agg, x, wp, bbef, blin, baft, out);
    }
}

// Round 13
// 605.459 us; speedup vs baseline: 1.1731x; 1.1731x over previous
//
#include <hip/hip_runtime.h>

#define EN 200000
#define TN 1500000
#define NCHUNK ((TN + 63) >> 6)
#define SCAN_BLK 512
#define NB ((EN + SCAN_BLK - 1) / SCAN_BLK)

typedef short s16x8 __attribute__((ext_vector_type(8)));
typedef float f32x4 __attribute__((ext_vector_type(4)));

// ---- packed weight offsets (ushort units) ----
#define WJI   0
#define WKJ   16384
#define WDOWN 32768
#define WUP   40960
#define WB0   49152
#define WB1   65536
#define WLIN  81920
#define WA00  98304
#define WA01  114688
#define WA10  131072
#define WA11  147456
#define WSBFP 163840
#define WP_COUNT 167936

// hardware bf16 convert (RNE) — fast path for VALU-bound edge kernels
__device__ __forceinline__ unsigned short f2bf(float f) {
    unsigned int r;
    asm("v_cvt_pk_bf16_f32 %0, %1, %1" : "=v"(r) : "v"(f));
    return (unsigned short)r;
}
// bit-twiddle RNE convert — used in k_mscat (A/B: asm variant cost 25% there)
__device__ __forceinline__ unsigned short f2bf_o(float f) {
    unsigned int b = __float_as_uint(f);
    b += 0x7FFFu + ((b >> 16) & 1u);
    return (unsigned short)(b >> 16);
}
__device__ __forceinline__ float bf2f(unsigned short u) {
    return __uint_as_float(((unsigned int)u) << 16);
}
__device__ __forceinline__ float silu_f(float v) {
    return v * __builtin_amdgcn_rcpf(1.f + __expf(-v));
}

#define MFMA(a, b, c) __builtin_amdgcn_mfma_f32_16x16x32_bf16((a), (b), (c), 0, 0, 0)

// ============ prep1: combine tiny basis weight pairs ============
__global__ void k_prep1(const float* __restrict__ Wr1, const float* __restrict__ Wr2,
                        const float* __restrict__ Ws1, const float* __restrict__ Ws2,
                        float* __restrict__ wrbfc, float* __restrict__ wsbfc) {
    int idx = blockIdx.x * 256 + threadIdx.x;
    if (idx < 768) {  // [6][128]
        int r = idx >> 7, c = idx & 127;
        float s = 0.f;
        #pragma unroll
        for (int m = 0; m < 8; m++) s += Wr1[r * 8 + m] * Wr2[m * 128 + c];
        wrbfc[idx] = s;
    }
    int i2 = idx - 768;
    if (i2 >= 0 && i2 < 2688) {  // [42][64]
        int r = i2 >> 6, c = i2 & 63;
        float s = 0.f;
        #pragma unroll
        for (int m = 0; m < 8; m++) s += Ws1[r * 8 + m] * Ws2[m * 64 + c];
        wsbfc[i2] = s;
    }
}

// ============ prep2: pack weights into MFMA B-fragment layout ============
__global__ void k_prep2(const float* __restrict__ Wji, const float* __restrict__ Wkj,
                        const float* __restrict__ Wdown, const float* __restrict__ Wup,
                        const float* __restrict__ Wbef, const float* __restrict__ Wlin,
                        const float* __restrict__ Waft, const float* __restrict__ wsbfc,
                        unsigned short* __restrict__ wp) {
    for (int idx = blockIdx.x * 256 + threadIdx.x; idx < WP_COUNT; idx += gridDim.x * 256) {
        const float* src;
        int off, N;
        bool pad42 = false;
        if (idx < WKJ)        { src = Wji;           off = WJI;   N = 128; }
        else if (idx < WDOWN) { src = Wkj;           off = WKJ;   N = 128; }
        else if (idx < WUP)   { src = Wdown;         off = WDOWN; N = 64;  }
        else if (idx < WB0)   { src = Wup;           off = WUP;   N = 128; }
        else if (idx < WB1)   { src = Wbef;          off = WB0;   N = 128; }
        else if (idx < WLIN)  { src = Wbef + 16384;  off = WB1;   N = 128; }
        else if (idx < WA00)  { src = Wlin;          off = WLIN;  N = 128; }
        else if (idx < WA01)  { src = Waft;          off = WA00;  N = 128; }
        else if (idx < WA10)  { src = Waft + 16384;  off = WA01;  N = 128; }
        else if (idx < WA11)  { src = Waft + 32768;  off = WA10;  N = 128; }
        else if (idx < WSBFP) { src = Waft + 49152;  off = WA11;  N = 128; }
        else                  { src = wsbfc;         off = WSBFP; N = 64; pad42 = true; }
        int li = idx - off;
        int j = li & 7, lane = (li >> 3) & 63, rest = li >> 9;
        int ncb = N >> 4;
        int cb = rest % ncb, ks = rest / ncb;
        int k = ks * 32 + ((lane >> 4) << 3) + j;
        int n = cb * 16 + (lane & 15);
        float v = 0.f;
        if (!pad42 || k < 42) v = src[k * N + n];
        wp[idx] = f2bf(v);
    }
}

// ============ K1: edge stage 1 ============
__global__ __launch_bounds__(256, 4) void k_edge1(
        const float* __restrict__ x, const float* __restrict__ rbf,
        const float* __restrict__ bkj, const float* __restrict__ bji,
        const unsigned short* __restrict__ wp, const float* __restrict__ wrbfc,
        float* __restrict__ xji, unsigned short* __restrict__ xd) {
    __shared__ unsigned short xa[64 * 136];
    __shared__ unsigned short kjt[64 * 136];   // holds rp first, then kj tile
    const int tid = threadIdx.x;
    const int row0 = blockIdx.x * 64;
    {
        const float4* src = (const float4*)(x + (size_t)row0 * 128);
        #pragma unroll
        for (int k = 0; k < 8; k++) {
            int idx = tid + k * 256;
            float4 v = src[idx];
            int flat = idx << 2, r = flat >> 7, c = flat & 127;
            ushort4 u; u.x = f2bf(v.x); u.y = f2bf(v.y); u.z = f2bf(v.z); u.w = f2bf(v.w);
            *(ushort4*)&xa[r * 136 + c] = u;
        }
    }
    #pragma unroll
    for (int k = 0; k < 32; k++) {
        int idx = tid + k * 256;
        int r = idx >> 7, c = idx & 127;
        const float* rb = rbf + (size_t)(row0 + r) * 6;
        float s = rb[0] * wrbfc[c] + rb[1] * wrbfc[128 + c] + rb[2] * wrbfc[256 + c]
                + rb[3] * wrbfc[384 + c] + rb[4] * wrbfc[512 + c] + rb[5] * wrbfc[640 + c];
        kjt[r * 136 + c] = f2bf(s);
    }
    __syncthreads();
    const int w = tid >> 6, l = tid & 63, l15 = l & 15, l4 = l >> 4;
    s16x8 af[4];
    {
        const unsigned short* ab = &xa[(w * 16 + l15) * 136 + l4 * 8];
        #pragma unroll
        for (int ks = 0; ks < 4; ks++) af[ks] = *(const s16x8*)(ab + ks * 32);
    }
    #pragma unroll
    for (int cb = 0; cb < 8; cb++) {
        f32x4 accj = {0.f, 0.f, 0.f, 0.f};
        f32x4 acck = {0.f, 0.f, 0.f, 0.f};
        #pragma unroll
        for (int ks = 0; ks < 4; ks++) {
            s16x8 bfj = *(const s16x8*)(wp + WJI + (((ks << 3) + cb) * 64 + l) * 8);
            s16x8 bfk = *(const s16x8*)(wp + WKJ + (((ks << 3) + cb) * 64 + l) * 8);
            accj = MFMA(af[ks], bfj, accj);
            acck = MFMA(af[ks], bfk, acck);
        }
        int col = (cb << 4) + l15;
        float bvj = bji[col];
        float bvk = bkj[col];
        #pragma unroll
        for (int i = 0; i < 4; i++) {
            int r = w * 16 + l4 * 4 + i;
            xji[(size_t)(row0 + r) * 128 + col] = silu_f(accj[i] + bvj);
            float rp = bf2f(kjt[r * 136 + col]);
            kjt[r * 136 + col] = f2bf(silu_f(acck[i] + bvk) * rp);
        }
    }
    __syncthreads();
    s16x8 ag[4];
    {
        const unsigned short* ab = &kjt[(w * 16 + l15) * 136 + l4 * 8];
        #pragma unroll
        for (int ks = 0; ks < 4; ks++) ag[ks] = *(const s16x8*)(ab + ks * 32);
    }
    #pragma unroll
    for (int cb = 0; cb < 4; cb++) {
        f32x4 acc = {0.f, 0.f, 0.f, 0.f};
        #pragma unroll
        for (int ks = 0; ks < 4; ks++) {
            s16x8 bf = *(const s16x8*)(wp + WDOWN + (((ks << 2) + cb) * 64 + l) * 8);
            acc = MFMA(ag[ks], bf, acc);
        }
        int col = (cb << 4) + l15;
        #pragma unroll
        for (int i = 0; i < 4; i++) {
            int r = w * 16 + l4 * 4 + i;
            xd[(size_t)(row0 + r) * 64 + col] = f2bf(silu_f(acc[i]));
        }
    }
}

// ============ sort phase ============
__global__ void k_hist(const int* __restrict__ iji, int* __restrict__ cnt) {
    for (int t = blockIdx.x * 256 + threadIdx.x; t < TN; t += gridDim.x * 256)
        atomicAdd(&cnt[iji[t]], 1);
}

__global__ __launch_bounds__(SCAN_BLK) void k_scan1(const int* __restrict__ cnt, int* __restrict__ bsum) {
    __shared__ int s[SCAN_BLK];
    int i = threadIdx.x, gi = blockIdx.x * SCAN_BLK + i;
    s[i] = (gi < EN) ? cnt[gi] : 0;
    __syncthreads();
    for (int d = SCAN_BLK >> 1; d > 0; d >>= 1) {
        if (i < d) s[i] += s[i + d];
        __syncthreads();
    }
    if (i == 0) bsum[blockIdx.x] = s[0];
}

__global__ __launch_bounds__(SCAN_BLK) void k_scan2(const int* __restrict__ bsum, int* __restrict__ bscan) {
    __shared__ int s[SCAN_BLK];
    int i = threadIdx.x;
    int v = (i < NB) ? bsum[i] : 0;
    s[i] = v;
    __syncthreads();
    for (int d = 1; d < SCAN_BLK; d <<= 1) {
        int t = (i >= d) ? s[i - d] : 0;
        __syncthreads();
        s[i] += t;
        __syncthreads();
    }
    if (i < NB) bscan[i] = s[i] - v;
}

__global__ __launch_bounds__(SCAN_BLK) void k_scan3(const int* __restrict__ cnt, const int* __restrict__ bscan,
                                                    int* __restrict__ segoff, int* __restrict__ cursor) {
    __shared__ int s[SCAN_BLK];
    int i = threadIdx.x, gi = blockIdx.x * SCAN_BLK + i;
    int c = (gi < EN) ? cnt[gi] : 0;
    s[i] = c;
    __syncthreads();
    for (int d = 1; d < SCAN_BLK; d <<= 1) {
        int t = (i >= d) ? s[i - d] : 0;
        __syncthreads();
        s[i] += t;
        __syncthreads();
    }
    int off = bscan[blockIdx.x] + s[i] - c;
    if (gi < EN) { segoff[gi] = off; cursor[gi] = off; }
    if (blockIdx.x == 0 && i == 0) segoff[EN] = TN;
}

__global__ void k_rank(const int* __restrict__ iji, int* __restrict__ cursor, int* __restrict__ pos) {
    for (int t = blockIdx.x * 256 + threadIdx.x; t < TN; t += gridDim.x * 256)
        pos[t] = atomicAdd(&cursor[iji[t]], 1);
}

// ============ K2a: sbf_p GEMM + xd gather + scattered m store ============
// R8 memory pattern + register double-buffered sbf prefetch (R12-verified).
__global__ __launch_bounds__(256) void k_mscat(
        const float* __restrict__ sbf, const int* __restrict__ ikj, const int* __restrict__ pos,
        const unsigned short* __restrict__ wp, const unsigned short* __restrict__ xd,
        unsigned short* __restrict__ msort) {
    __shared__ unsigned short sb[64 * 72];
    const int tid = threadIdx.x;
    const int w = tid >> 6, l = tid & 63, l15 = l & 15, l4 = l >> 4;
    for (int idx = tid; idx < 64 * 72; idx += 256) sb[idx] = 0;
    __syncthreads();
    int ch = blockIdx.x;
    float pf[11];
    if (ch < NCHUNK) {
        const float* src = sbf + (size_t)(ch << 6) * 42;
        int lim = min(2688, (TN - (ch << 6)) * 42);
        #pragma unroll
        for (int k = 0; k < 11; k++) {
            int idx = tid + (k << 8);
            pf[k] = (idx < lim) ? src[idx] : 0.f;
        }
    }
    for (; ch < NCHUNK; ch += gridDim.x) {
        const int t0 = ch << 6;
        const int nt = min(64, TN - t0);
        const int tot = nt * 42;
        #pragma unroll
        for (int k = 0; k < 11; k++) {
            int idx = tid + (k << 8);
            if (idx < tot) {
                int r = idx / 42, c = idx - r * 42;
                sb[r * 72 + c] = f2bf_o(pf[k]);
            }
        }
        __syncthreads();
        s16x8 afr[2];
        {
            const unsigned short* ab = &sb[(w * 16 + l15) * 72 + l4 * 8];
            afr[0] = *(const s16x8*)ab;
            afr[1] = *(const s16x8*)(ab + 32);
        }
        f32x4 accs[4];
        #pragma unroll
        for (int cb = 0; cb < 4; cb++) {
            f32x4 acc = {0.f, 0.f, 0.f, 0.f};
            acc = MFMA(afr[0], *(const s16x8*)(wp + WSBFP + ((cb) * 64 + l) * 8), acc);
            acc = MFMA(afr[1], *(const s16x8*)(wp + WSBFP + ((4 + cb) * 64 + l) * 8), acc);
            accs[cb] = acc;
        }
        // prefetch next chunk (overlaps the gather/scatter below)
        int nch = ch + gridDim.x;
        if (nch < NCHUNK) {
            const float* nsrc = sbf + (size_t)(nch << 6) * 42;
            int nlim = min(2688, (TN - (nch << 6)) * 42);
            #pragma unroll
            for (int k = 0; k < 11; k++) {
                int idx = tid + (k << 8);
                pf[k] = (idx < nlim) ? nsrc[idx] : 0.f;
            }
        }
        #pragma unroll
        for (int i = 0; i < 4; i++) {
            int r = w * 16 + l4 * 4 + i;
            if (r < nt) {
                int t = t0 + r;
                int a = ikj[t];
                size_t mb = (size_t)pos[t] * 64;
                const unsigned short* xr = xd + (size_t)a * 64;
                #pragma unroll
                for (int cb = 0; cb < 4; cb++) {
                    int col = (cb << 4) + l15;
                    msort[mb + col] = f2bf_o(accs[cb][i] * bf2f(xr[col]));
                }
            }
        }
        __syncthreads();
    }
}

// ============ K2b: segment reduce (contiguous runs, dword loads; R8-verified) ============
__global__ __launch_bounds__(256) void k_seg(
        const unsigned short* __restrict__ msort, const int* __restrict__ segoff,
        float* __restrict__ agg) {
    int e = blockIdx.x * 4 + (threadIdx.x >> 6);
    if (e >= EN) return;
    int l = threadIdx.x & 63;
    int sub = l >> 5, c2 = l & 31;
    int n0 = segoff[e], n1 = segoff[e + 1];
    float a0 = 0.f, a1 = 0.f;
    for (int p = n0 + sub; p < n1; p += 2) {
        unsigned int u = *(const unsigned int*)(msort + (size_t)p * 64 + c2 * 2);
        a0 += bf2f((unsigned short)(u & 0xFFFF));
        a1 += bf2f((unsigned short)(u >> 16));
    }
    a0 += __shfl_xor(a0, 32, 64);
    a1 += __shfl_xor(a1, 32, 64);
    if (sub == 0) {
        float2 o = {a0, a1};
        *(float2*)(agg + (size_t)e * 64 + c2 * 2) = o;
    }
}

// ============ fallback: atomic scatter ============
__global__ __launch_bounds__(256) void k_trip(
        const float* __restrict__ sbf, const int* __restrict__ ikj, const int* __restrict__ iji,
        const unsigned short* __restrict__ wp, const unsigned short* __restrict__ xd,
        float* __restrict__ agg) {
    __shared__ unsigned short sb[64 * 72];
    const int tid = threadIdx.x;
    const int w = tid >> 6, l = tid & 63, l15 = l & 15, l4 = l >> 4;
    for (int idx = tid; idx < 64 * 72; idx += 256) sb[idx] = 0;
    __syncthreads();
    for (int ch = blockIdx.x; ch < NCHUNK; ch += gridDim.x) {
        const int t0 = ch << 6;
        const int nt = min(64, TN - t0);
        const int tot = nt * 42;
        const float* src = sbf + (size_t)t0 * 42;
        for (int idx = tid; idx < tot; idx += 256) {
            int r = idx / 42, c = idx - r * 42;
            sb[r * 72 + c] = f2bf_o(src[idx]);
        }
        __syncthreads();
        s16x8 afr[2];
        {
            const unsigned short* ab = &sb[(w * 16 + l15) * 72 + l4 * 8];
            afr[0] = *(const s16x8*)ab;
            afr[1] = *(const s16x8*)(ab + 32);
        }
        #pragma unroll
        for (int cb = 0; cb < 4; cb++) {
            f32x4 acc = {0.f, 0.f, 0.f, 0.f};
            acc = MFMA(afr[0], *(const s16x8*)(wp + WSBFP + ((cb) * 64 + l) * 8), acc);
            acc = MFMA(afr[1], *(const s16x8*)(wp + WSBFP + ((4 + cb) * 64 + l) * 8), acc);
            int col = (cb << 4) + l15;
            #pragma unroll
            for (int i = 0; i < 4; i++) {
                int r = w * 16 + l4 * 4 + i;
                if (r < nt) {
                    int t = t0 + r;
                    int a = ikj[t], g = iji[t];
                    float m = acc[i] * bf2f(xd[(size_t)a * 64 + col]);
                    atomicAdd(&agg[(size_t)g * 64 + col], m);
                }
            }
        }
        __syncthreads();
    }
}

// residual MLP layer, h in registers; phases barrier-separated.
__device__ __forceinline__ void layer_reg(float (*h)[4], unsigned short* s0, unsigned short* s1,
                                          const unsigned short* wp0, const float* b0,
                                          const unsigned short* wp1, const float* b1,
                                          int w, int l, int l15, int l4) {
    #pragma unroll
    for (int cb = 0; cb < 8; cb++) {
        int col = (cb << 4) + l15;
        #pragma unroll
        for (int i = 0; i < 4; i++)
            s0[((w << 4) + (l4 << 2) + i) * 136 + col] = f2bf(h[cb][i]);
    }
    __syncthreads();
    {
        const unsigned short* ab = &s0[((w << 4) + l15) * 136 + (l4 << 3)];
        s16x8 a0 = *(const s16x8*)ab, a1 = *(const s16x8*)(ab + 32);
        s16x8 a2 = *(const s16x8*)(ab + 64), a3 = *(const s16x8*)(ab + 96);
        #pragma unroll
        for (int cb = 0; cb < 8; cb++) {
            f32x4 acc = {0.f, 0.f, 0.f, 0.f};
            acc = MFMA(a0, *(const s16x8*)(wp0 + ((cb) * 64 + l) * 8), acc);
            acc = MFMA(a1, *(const s16x8*)(wp0 + ((8 + cb) * 64 + l) * 8), acc);
            acc = MFMA(a2, *(const s16x8*)(wp0 + ((16 + cb) * 64 + l) * 8), acc);
            acc = MFMA(a3, *(const s16x8*)(wp0 + ((24 + cb) * 64 + l) * 8), acc);
            int col = (cb << 4) + l15;
            float bv = b0[col];
            #pragma unroll
            for (int i = 0; i < 4; i++)
                s1[((w << 4) + (l4 << 2) + i) * 136 + col] = f2bf(silu_f(acc[i] + bv));
        }
    }
    __syncthreads();
    {
        const unsigned short* ab = &s1[((w << 4) + l15) * 136 + (l4 << 3)];
        s16x8 a0 = *(const s16x8*)ab, a1 = *(const s16x8*)(ab + 32);
        s16x8 a2 = *(const s16x8*)(ab + 64), a3 = *(const s16x8*)(ab + 96);
        #pragma unroll
        for (int cb = 0; cb < 8; cb++) {
            f32x4 acc = {0.f, 0.f, 0.f, 0.f};
            acc = MFMA(a0, *(const s16x8*)(wp1 + ((cb) * 64 + l) * 8), acc);
            acc = MFMA(a1, *(const s16x8*)(wp1 + ((8 + cb) * 64 + l) * 8), acc);
            acc = MFMA(a2, *(const s16x8*)(wp1 + ((16 + cb) * 64 + l) * 8), acc);
            acc = MFMA(a3, *(const s16x8*)(wp1 + ((24 + cb) * 64 + l) * 8), acc);
            int col = (cb << 4) + l15;
            float bv = b1[col];
            #pragma unroll
            for (int i = 0; i < 4; i++) h[cb][i] += silu_f(acc[i] + bv);
        }
    }
    __syncthreads();
}

// ============ K3: edge stage 2, register-resident residual ============
__global__ __launch_bounds__(256, 4) void k_edge2(
        const float* __restrict__ agg, const float* __restrict__ x,
        const unsigned short* __restrict__ wp, const float* __restrict__ bbef,
        const float* __restrict__ blin, const float* __restrict__ baft,
        float* __restrict__ out) {
    __shared__ unsigned short aa[64 * 136];
    __shared__ unsigned short bb[64 * 136];
    const int tid = threadIdx.x;
    const int row0 = blockIdx.x * 64;
    const int w = tid >> 6, l = tid & 63, l15 = l & 15, l4 = l >> 4;
    {
        const float4* src = (const float4*)(agg + (size_t)row0 * 64);
        #pragma unroll
        for (int k = 0; k < 4; k++) {
            int idx = tid + k * 256;
            float4 v = src[idx];
            int flat = idx << 2, r = flat >> 6, c = flat & 63;
            ushort4 u; u.x = f2bf(v.x); u.y = f2bf(v.y); u.z = f2bf(v.z); u.w = f2bf(v.w);
            *(ushort4*)&aa[r * 72 + c] = u;
        }
    }
    float h[8][4];
    #pragma unroll
    for (int cb = 0; cb < 8; cb++) {
        int col = (cb << 4) + l15;
        #pragma unroll
        for (int i = 0; i < 4; i++) {
            int r = (w << 4) + (l4 << 2) + i;
            h[cb][i] = out[(size_t)(row0 + r) * 128 + col];
        }
    }
    __syncthreads();
    {
        const unsigned short* ab = &aa[((w << 4) + l15) * 72 + (l4 << 3)];
        s16x8 a0 = *(const s16x8*)ab, a1 = *(const s16x8*)(ab + 32);
        #pragma unroll
        for (int cb = 0; cb < 8; cb++) {
            f32x4 acc = {0.f, 0.f, 0.f, 0.f};
            acc = MFMA(a0, *(const s16x8*)(wp + WUP + ((cb) * 64 + l) * 8), acc);
            acc = MFMA(a1, *(const s16x8*)(wp + WUP + ((8 + cb) * 64 + l) * 8), acc);
            #pragma unroll
            for (int i = 0; i < 4; i++) h[cb][i] += silu_f(acc[i]);
        }
    }
    __syncthreads();
    layer_reg(h, bb, aa, wp + WB0, bbef, wp + WB1, bbef + 128, w, l, l15, l4);
    #pragma unroll
    for (int cb = 0; cb < 8; cb++) {
        int col = (cb << 4) + l15;
        #pragma unroll
        for (int i = 0; i < 4; i++)
            bb[((w << 4) + (l4 << 2) + i) * 136 + col] = f2bf(h[cb][i]);
    }
    __syncthreads();
    {
        const unsigned short* ab = &bb[((w << 4) + l15) * 136 + (l4 << 3)];
        s16x8 a0 = *(const s16x8*)ab, a1 = *(const s16x8*)(ab + 32);
        s16x8 a2 = *(const s16x8*)(ab + 64), a3 = *(const s16x8*)(ab + 96);
        #pragma unroll
        for (int cb = 0; cb < 8; cb++) {
            f32x4 acc = {0.f, 0.f, 0.f, 0.f};
            acc = MFMA(a0, *(const s16x8*)(wp + WLIN + ((cb) * 64 + l) * 8), acc);
            acc = MFMA(a1, *(const s16x8*)(wp + WLIN + ((8 + cb) * 64 + l) * 8), acc);
            acc = MFMA(a2, *(const s16x8*)(wp + WLIN + ((16 + cb) * 64 + l) * 8), acc);
            acc = MFMA(a3, *(const s16x8*)(wp + WLIN + ((24 + cb) * 64 + l) * 8), acc);
            int col = (cb << 4) + l15;
            float bv = blin[col];
            #pragma unroll
            for (int i = 0; i < 4; i++) {
                int r = (w << 4) + (l4 << 2) + i;
                h[cb][i] = silu_f(acc[i] + bv) + x[(size_t)(row0 + r) * 128 + col];
            }
        }
    }
    __syncthreads();
    layer_reg(h, aa, bb, wp + WA00, baft, wp + WA01, baft + 128, w, l, l15, l4);
    layer_reg(h, aa, bb, wp + WA10, baft + 256, wp + WA11, baft + 384, w, l, l15, l4);
    #pragma unroll
    for (int cb = 0; cb < 8; cb++) {
        int col = (cb << 4) + l15;
        #pragma unroll
        for (int i = 0; i < 4; i++) {
            int r = (w << 4) + (l4 << 2) + i;
            out[(size_t)(row0 + r) * 128 + col] = h[cb][i];
        }
    }
}

extern "C" void kernel_launch(void* const* d_in, const int* in_sizes, int n_in,
                              void* d_out, int out_size, void* d_ws, size_t ws_size,
                              hipStream_t stream) {
    const float* x     = (const float*)d_in[0];
    const float* rbf   = (const float*)d_in[1];
    const float* sbf   = (const float*)d_in[2];
    const int*   ikj   = (const int*)d_in[3];
    const int*   iji   = (const int*)d_in[4];
    const float* Wr1   = (const float*)d_in[5];
    const float* Wr2   = (const float*)d_in[6];
    const float* Ws1   = (const float*)d_in[7];
    const float* Ws2   = (const float*)d_in[8];
    const float* Wkj   = (const float*)d_in[9];
    const float* bkj   = (const float*)d_in[10];
    const float* Wji   = (const float*)d_in[11];
    const float* bji   = (const float*)d_in[12];
    const float* Wdown = (const float*)d_in[13];
    const float* Wup   = (const float*)d_in[14];
    const float* Wbef  = (const float*)d_in[15];
    const float* bbef  = (const float*)d_in[16];
    const float* Wlin  = (const float*)d_in[17];
    const float* blin  = (const float*)d_in[18];
    const float* Waft  = (const float*)d_in[19];
    const float* baft  = (const float*)d_in[20];

    char* ws = (char*)d_ws;
    size_t o = 0;
    auto alloc = [&](size_t bytes) { size_t r = o; o = (o + bytes + 255) & ~(size_t)255; return r; };
    size_t o_agg   = alloc((size_t)EN * 64 * 4);
    size_t o_xd    = alloc((size_t)EN * 64 * 2);
    size_t o_wp    = alloc((size_t)WP_COUNT * 2);
    size_t o_wrbfc = alloc(768 * 4);
    size_t o_wsbfc = alloc(2688 * 4);
    size_t o_cnt   = alloc((size_t)EN * 4);
    size_t o_soff  = alloc((size_t)(EN + 1) * 4);
    size_t o_cur   = alloc((size_t)EN * 4);
    size_t o_bsum  = alloc(SCAN_BLK * 4);
    size_t o_bscan = alloc(SCAN_BLK * 4);
    size_t o_pos   = alloc((size_t)TN * 4);
    size_t o_msort = alloc((size_t)TN * 64 * 2);
    size_t need_sorted = o;

    float* agg          = (float*)(ws + o_agg);
    unsigned short* xd  = (unsigned short*)(ws + o_xd);
    unsigned short* wp  = (unsigned short*)(ws + o_wp);
    float* wrbfc        = (float*)(ws + o_wrbfc);
    float* wsbfc        = (float*)(ws + o_wsbfc);
    int* cnt            = (int*)(ws + o_cnt);
    int* segoff         = (int*)(ws + o_soff);
    int* cursor         = (int*)(ws + o_cur);
    int* bsum           = (int*)(ws + o_bsum);
    int* bscan          = (int*)(ws + o_bscan);
    int* pos            = (int*)(ws + o_pos);
    unsigned short* msort = (unsigned short*)(ws + o_msort);
    float* out          = (float*)d_out;

    k_prep1<<<14, 256, 0, stream>>>(Wr1, Wr2, Ws1, Ws2, wrbfc, wsbfc);
    k_prep2<<<656, 256, 0, stream>>>(Wji, Wkj, Wdown, Wup, Wbef, Wlin, Waft, wsbfc, wp);
    k_edge1<<<EN / 64, 256, 0, stream>>>(x, rbf, bkj, bji, wp, wrbfc, out, xd);

    if (ws_size >= need_sorted) {
        hipMemsetAsync(cnt, 0, (size_t)EN * 4, stream);
        k_hist<<<2048, 256, 0, stream>>>(iji, cnt);
        k_scan1<<<NB, SCAN_BLK, 0, stream>>>(cnt, bsum);
        k_scan2<<<1, SCAN_BLK, 0, stream>>>(bsum, bscan);
        k_scan3<<<NB, SCAN_BLK, 0, stream>>>(cnt, bscan, segoff, cursor);
        k_rank<<<2048, 256, 0, stream>>>(iji, cursor, pos);
        k_mscat<<<4096, 256, 0, stream>>>(sbf, ikj, pos, wp, xd, msort);
        k_seg<<<(EN + 3) / 4, 256, 0, stream>>>(msort, segoff, agg);
    } else {
        hipMemsetAsync(agg, 0, (size_t)EN * 64 * 4, stream);
        k_trip<<<4096, 256, 0, stream>>>(sbf, ikj, iji, wp, xd, agg);
        k_edge2<<<EN / 64, 256, 0, stream>>>(agg, x, wp, bbef, blin, baft, out);
        return;
    }

    k_edge2<<<EN / 64, 256, 0, stream>>>(agg, x, wp, bbef, blin, baft, out);
}